// Round 21
// baseline (202.857 us; speedup 1.0000x reference)
//
#include <hip/hip_runtime.h>
#include <hip/hip_fp16.h>
#include <math.h>

#define NN 50000
#define EE 800000
#define NB 196   // ceil(NN/256)
#define NBK 128  // dst-range buckets
#define BKN 391  // nodes per bucket (128*391 = 50048 >= NN)
#define CH 4096  // edges per bucket_stage block
// IN_DIM = 128, HEADS*HIDDEN = 128, NUM_CLASSES = 10

typedef _Float16 f16x8 __attribute__((ext_vector_type(8)));
typedef float f32x4 __attribute__((ext_vector_type(4)));
typedef float f32x2 __attribute__((ext_vector_type(2)));

__device__ inline float elu1(float x) { return x > 0.f ? x : expm1f(x); }

// ---------- prep: x (f32) -> xh (f16), dst-degree histogram hidden under the stream ----------
__global__ __launch_bounds__(256) void convert_x_deg(
    const float* __restrict__ x, __half* __restrict__ xh,
    const int* __restrict__ dst, int* __restrict__ deg)
{
    const int i = blockIdx.x * 256 + threadIdx.x;  // float4 index
    if (i < NN * 32) {
        const float4 v = ((const float4*)x)[i];
        ((__half2*)xh)[i * 2] = __floats2half2_rn(v.x, v.y);
        ((__half2*)xh)[i * 2 + 1] = __floats2half2_rn(v.z, v.w);
    }
    if (i < EE) atomicAdd(&deg[dst[i]], 1);
}

// ---------- prep: W1 transpose (f16) + W2 pack (f16, zero-padded) in one kernel ----------
__global__ __launch_bounds__(256) void build_weights(
    const float* __restrict__ Wq, const float* __restrict__ Wk,
    const float* __restrict__ Wv, const float* __restrict__ Ws,
    const float* __restrict__ Wq2, const float* __restrict__ bq2,
    const float* __restrict__ Wk2, const float* __restrict__ bk2,
    const float* __restrict__ Wv2, const float* __restrict__ bv2,
    const float* __restrict__ Ws2, const float* __restrict__ bs2,
    __half* __restrict__ Wt, __half* __restrict__ W2t, float* __restrict__ bias2)
{
    const int idx = blockIdx.x * 256 + threadIdx.x;
    if (idx < 8192) {
        const int col = idx >> 7, k = idx & 127;
        const int m = col >> 4, j = col & 15;
        const float* W = m == 0 ? Wq2 : m == 1 ? Wk2 : m == 2 ? Wv2 : Ws2;
        W2t[idx] = (__half)(j < 10 ? W[k * 10 + j] : 0.f);
    }
    if (idx < 64) {
        const int m = idx >> 4, j = idx & 15;
        const float* b = m == 0 ? bq2 : m == 1 ? bk2 : m == 2 ? bv2 : bs2;
        bias2[idx] = j < 10 ? b[j] : 0.f;
    }
    __shared__ float tile[32][33];
    const int mat = blockIdx.x >> 4;
    const int tid = blockIdx.x & 15;
    const int k0 = (tid >> 2) * 32, c0 = (tid & 3) * 32;
    const float* W = mat == 0 ? Wq : mat == 1 ? Wk : mat == 2 ? Wv : Ws;
    const int r = threadIdx.x >> 5;   // 0..7
    const int c = threadIdx.x & 31;
    for (int rr = r; rr < 32; rr += 8) tile[rr][c] = W[(size_t)(k0 + rr) * 128 + c0 + c];
    __syncthreads();
    for (int rr = r; rr < 32; rr += 8)
        Wt[((size_t)mat * 128 + c0 + rr) * 128 + k0 + c] = (__half)tile[c][rr];
}

// ---------- CSR build: multi-block scan ----------
__global__ __launch_bounds__(256) void block_sums(
    const int* __restrict__ deg, int* __restrict__ bsum)
{
    __shared__ int ws[4];
    const int t = threadIdx.x;
    const int idx = blockIdx.x * 256 + t;
    int d = (idx < NN) ? deg[idx] : 0;
    #pragma unroll
    for (int off = 32; off; off >>= 1) d += __shfl_down(d, off, 64);
    if ((t & 63) == 0) ws[t >> 6] = d;
    __syncthreads();
    if (t == 0) bsum[blockIdx.x] = ws[0] + ws[1] + ws[2] + ws[3];
}

__global__ __launch_bounds__(256) void scan_bsums(int* __restrict__ bsum)
{
    __shared__ int s[256];
    const int t = threadIdx.x;
    int v = (t < NB) ? bsum[t] : 0;
    s[t] = v;
    __syncthreads();
    for (int off = 1; off < 256; off <<= 1) {
        int u = (t >= off) ? s[t - off] : 0;
        __syncthreads();
        s[t] += u;
        __syncthreads();
    }
    if (t < NB) bsum[t] = (t == 0) ? 0 : s[t - 1];
}

// rowptr + bucket cursors (bcur[b] = rowptr[b*BKN], bucket base in esrc/bpair)
__global__ __launch_bounds__(256) void write_rowptr(
    const int* __restrict__ deg, const int* __restrict__ bsum,
    int* __restrict__ rowptr, int* __restrict__ bcur)
{
    __shared__ int s[256];
    const int t = threadIdx.x;
    const int idx = blockIdx.x * 256 + t;
    const int d = (idx < NN) ? deg[idx] : 0;
    s[t] = d;
    __syncthreads();
    for (int off = 1; off < 256; off <<= 1) {
        int u = (t >= off) ? s[t - off] : 0;
        __syncthreads();
        s[t] += u;
        __syncthreads();
    }
    const int excl = ((t == 0) ? 0 : s[t - 1]) + bsum[blockIdx.x];
    if (idx < NN) {
        rowptr[idx] = excl;
        if (idx % BKN == 0) bcur[idx / BKN] = excl;
    }
    if (idx == NN - 1) rowptr[NN] = excl + d;  // == EE
}

// ---------- pass 1: bucket edges by dst range ----------
__global__ __launch_bounds__(256) void bucket_stage(
    const int* __restrict__ src, const int* __restrict__ dst,
    int* __restrict__ bcur, unsigned* __restrict__ bpair)
{
    __shared__ unsigned ep[CH];        // packed (dst<<16)|src
    __shared__ unsigned short eb[CH];  // bucket id
    __shared__ unsigned stg[CH];       // bucket-sorted
    __shared__ int cnt[NBK], off[NBK], pos[NBK], gbase[NBK];
    const int t = threadIdx.x;
    const int e0 = blockIdx.x * CH;
    const int n = min(CH, EE - e0);
    if (t < NBK) cnt[t] = 0;
    __syncthreads();
    for (int i = t; i < n; i += 256) {
        const int s = src[e0 + i], d = dst[e0 + i];
        ep[i] = (unsigned)s | ((unsigned)d << 16);
        const int b = d / BKN;
        eb[i] = (unsigned short)b;
        atomicAdd(&cnt[b], 1);
    }
    __syncthreads();
    if (t == 0) {
        int run = 0;
        for (int b = 0; b < NBK; ++b) { off[b] = run; pos[b] = run; run += cnt[b]; }
    }
    __syncthreads();
    if (t < NBK && cnt[t] > 0) gbase[t] = atomicAdd(&bcur[t], cnt[t]);
    __syncthreads();
    for (int i = t; i < n; i += 256) {
        const int b = eb[i];
        const int p = atomicAdd(&pos[b], 1);
        stg[p] = ep[i];
    }
    __syncthreads();
    for (int i = t; i < n; i += 256) {
        int lo = 0, hi = NBK - 1;
        while (lo < hi) { const int mid = (lo + hi + 1) >> 1; if (off[mid] <= i) lo = mid; else hi = mid - 1; }
        bpair[gbase[lo] + (i - off[lo])] = stg[i];
    }
}

// ---------- pass 2: one block per bucket; LDS cursors; esrc range exclusive ----------
__global__ __launch_bounds__(256) void bucket_scatter(
    const unsigned* __restrict__ bpair, const int* __restrict__ rowptr,
    int* __restrict__ esrc)
{
    __shared__ int lcur[BKN];
    const int b = blockIdx.x;
    const int n0 = b * BKN;
    const int n1 = min(NN, n0 + BKN);
    const int nn = n1 - n0;
    const int t = threadIdx.x;
    for (int i = t; i < nn; i += 256) lcur[i] = rowptr[n0 + i];
    __syncthreads();
    const int ebeg = rowptr[n0];
    const int eend = rowptr[n1];
    for (int i = ebeg + t; i < eend; i += 256) {
        const unsigned p = bpair[i];
        const int s = (int)(p & 0xFFFFu);
        const int d = (int)(p >> 16);
        const int pos = atomicAdd(&lcur[d - n0], 1);
        esrc[pos] = s;
    }
}

// ---------- layer-1 projections via MFMA: 2 mats per block, 4 waves x 32 rows ----------
// 256 threads (8 waves/CU at 34KB LDS) for store-latency hiding at constant traffic.
// q/skip f16; k/v fp8 e4m3. LDS-staged full-line stores.
__global__ __launch_bounds__(256) void gemm_l1_mfma(
    const __half* __restrict__ xh, const __half* __restrict__ Wt,
    const float* __restrict__ bq, const float* __restrict__ bk,
    const float* __restrict__ bv, const float* __restrict__ bs,
    __half* __restrict__ oqh, unsigned char* __restrict__ ok8,
    unsigned char* __restrict__ ov8, __half* __restrict__ osh)
{
    __shared__ __align__(16) unsigned char ldsraw[128 * 272];  // 34 KB
    const int pair = blockIdx.y;  // 0: mats {0(q f16),1(k fp8)}; 1: mats {2(v fp8),3(s f16)}
    const int t = threadIdx.x;
    const int wave = t >> 6;   // 0..3
    const int lane = t & 63;
    const int l = lane & 15;
    const int g = lane >> 4;  // 0..3
    const int brow0 = blockIdx.x * 128;
    const int wrow0 = brow0 + wave * 32;

    f16x8 xf[2][4];
    #pragma unroll
    for (int rt = 0; rt < 2; ++rt) {
        int arow = wrow0 + rt * 16 + l;
        if (arow >= NN) arow = NN - 1;  // clamp: garbage rows never stored
        #pragma unroll
        for (int kk = 0; kk < 4; ++kk)
            xf[rt][kk] = *(const f16x8*)((const _Float16*)xh + (size_t)arow * 128 + kk * 32 + g * 8);
    }

    for (int mi = 0; mi < 2; ++mi) {
        const int mat = pair * 2 + mi;
        const bool isfp8 = (mat == 1 || mat == 2);
        const float* b = mat == 0 ? bq : mat == 1 ? bk : mat == 2 ? bv : bs;
        const _Float16* wt = (const _Float16*)Wt + (size_t)mat * 128 * 128;

        f16x8 wf[4], wfn[4];
        #pragma unroll
        for (int kk = 0; kk < 4; ++kk)
            wf[kk] = *(const f16x8*)(wt + (size_t)l * 128 + kk * 32 + g * 8);

        for (int ct = 0; ct < 8; ++ct) {
            if (ct < 7) {
                const int ncol = (ct + 1) * 16 + l;
                #pragma unroll
                for (int kk = 0; kk < 4; ++kk)
                    wfn[kk] = *(const f16x8*)(wt + (size_t)ncol * 128 + kk * 32 + g * 8);
            }
            f32x4 acc[2];
            #pragma unroll
            for (int rt = 0; rt < 2; ++rt) acc[rt] = (f32x4){0.f, 0.f, 0.f, 0.f};
            #pragma unroll
            for (int kk = 0; kk < 4; ++kk)
                #pragma unroll
                for (int rt = 0; rt < 2; ++rt)
                    acc[rt] = __builtin_amdgcn_mfma_f32_16x16x32_f16(wf[kk], xf[rt][kk], acc[rt], 0, 0, 0);

            const int col0 = ct * 16 + g * 4;
            const float4 bias = *(const float4*)(b + col0);
            #pragma unroll
            for (int rt = 0; rt < 2; ++rt) {
                const int lrow = wave * 32 + rt * 16 + l;
                const float r0 = acc[rt][0] + bias.x;
                const float r1 = acc[rt][1] + bias.y;
                const float r2 = acc[rt][2] + bias.z;
                const float r3 = acc[rt][3] + bias.w;
                if (isfp8) {
                    int p = __builtin_amdgcn_cvt_pk_fp8_f32(r0, r1, 0, false);
                    p = __builtin_amdgcn_cvt_pk_fp8_f32(r2, r3, p, true);
                    *(int*)&ldsraw[lrow * 144 + col0] = p;       // 144B row stride
                } else {
                    __half2 h01 = __floats2half2_rn(r0, r1);
                    __half2 h23 = __floats2half2_rn(r2, r3);
                    uint2 u;
                    u.x = *(unsigned*)&h01;
                    u.y = *(unsigned*)&h23;
                    *(uint2*)&ldsraw[lrow * 272 + col0 * 2] = u; // 272B row stride
                }
            }
            #pragma unroll
            for (int kk = 0; kk < 4; ++kk) wf[kk] = wfn[kk];
        }

        __syncthreads();
        if (isfp8) {
            unsigned char* o = (mat == 1) ? ok8 : ov8;
            // 128 rows x 128B = 1024 16B units, 4 iters x 256 threads
            #pragma unroll
            for (int i = 0; i < 4; ++i) {
                const int idx = i * 256 + t;
                const int row = idx >> 3;
                const int seg = idx & 7;
                const int grow = brow0 + row;
                if (grow < NN)
                    *(uint4*)(o + (size_t)grow * 128 + seg * 16) = *(const uint4*)&ldsraw[row * 144 + seg * 16];
            }
        } else {
            __half* o = (mat == 0) ? oqh : osh;
            // 128 rows x 256B = 2048 16B units, 8 iters x 256 threads
            #pragma unroll
            for (int i = 0; i < 8; ++i) {
                const int idx = i * 256 + t;
                const int row = idx >> 4;
                const int seg = idx & 15;
                const int grow = brow0 + row;
                if (grow < NN)
                    *(uint4*)(o + (size_t)grow * 128 + seg * 8) = *(const uint4*)&ldsraw[row * 272 + seg * 16];
            }
        }
        __syncthreads();
    }
}

// ---------- layer-1 fused attention + skip + ELU -> h (fp16) ----------
// 32 lanes/dst x 4 fp8 channels/lane; head = 8 lanes -> 3-shfl reduce.
__global__ __launch_bounds__(256) void node_attn1(
    const __half* __restrict__ q1, const unsigned char* __restrict__ k8,
    const unsigned char* __restrict__ v8,
    const int* __restrict__ rowptr, const int* __restrict__ esrc,
    const __half* __restrict__ skiph,  // x @ Ws + bs (f16)
    __half* __restrict__ hb)           // out: h = elu(skip + attn), fp16
{
    const int t = threadIdx.x;
    const int d = blockIdx.x * 8 + (t >> 5);
    if (d >= NN) return;
    const int ch4 = (t & 31) << 2;  // channel base (4 channels/lane)

    const int beg = rowptr[d];
    const int end = rowptr[d + 1];

    float q0, q1v, q2, q3;
    {
        const __half2 qa = *(const __half2*)(q1 + (size_t)d * 128 + ch4);
        const __half2 qb = *(const __half2*)(q1 + (size_t)d * 128 + ch4 + 2);
        const float2 fa = __half22float2(qa);
        const float2 fb = __half22float2(qb);
        q0 = fa.x * 0.17677669529663687f;
        q1v = fa.y * 0.17677669529663687f;
        q2 = fb.x * 0.17677669529663687f;
        q3 = fb.y * 0.17677669529663687f;
    }

    f32x4 accA = {0.f, 0.f, 0.f, 0.f}, accB = {0.f, 0.f, 0.f, 0.f};
    float sA = 0.f, sB = 0.f;

    int i = beg;
    int sa = (i < end) ? esrc[i] : 0;
    int sb = (i + 1 < end) ? esrc[i + 1] : 0;
    unsigned kA = *(const unsigned*)(k8 + (size_t)sa * 128 + ch4);
    unsigned vA = *(const unsigned*)(v8 + (size_t)sa * 128 + ch4);
    unsigned kB = *(const unsigned*)(k8 + (size_t)sb * 128 + ch4);
    unsigned vB = *(const unsigned*)(v8 + (size_t)sb * 128 + ch4);

    while (i + 1 < end) {
        const int ni = i + 2;
        const int nsa = (ni < end) ? esrc[ni] : 0;
        const int nsb = (ni + 1 < end) ? esrc[ni + 1] : 0;
        const unsigned nkA = *(const unsigned*)(k8 + (size_t)nsa * 128 + ch4);
        const unsigned nvA = *(const unsigned*)(v8 + (size_t)nsa * 128 + ch4);
        const unsigned nkB = *(const unsigned*)(k8 + (size_t)nsb * 128 + ch4);
        const unsigned nvB = *(const unsigned*)(v8 + (size_t)nsb * 128 + ch4);

        const f32x2 kA01 = __builtin_amdgcn_cvt_pk_f32_fp8((int)kA, false);
        const f32x2 kA23 = __builtin_amdgcn_cvt_pk_f32_fp8((int)kA, true);
        const f32x2 kB01 = __builtin_amdgcn_cvt_pk_f32_fp8((int)kB, false);
        const f32x2 kB23 = __builtin_amdgcn_cvt_pk_f32_fp8((int)kB, true);

        float pA = q0 * kA01[0] + q1v * kA01[1] + q2 * kA23[0] + q3 * kA23[1];
        float pB = q0 * kB01[0] + q1v * kB01[1] + q2 * kB23[0] + q3 * kB23[1];
        pA += __shfl_xor(pA, 4, 8); pB += __shfl_xor(pB, 4, 8);
        pA += __shfl_xor(pA, 2, 8); pB += __shfl_xor(pB, 2, 8);
        pA += __shfl_xor(pA, 1, 8); pB += __shfl_xor(pB, 1, 8);

        const f32x2 vA01 = __builtin_amdgcn_cvt_pk_f32_fp8((int)vA, false);
        const f32x2 vA23 = __builtin_amdgcn_cvt_pk_f32_fp8((int)vA, true);
        const f32x2 vB01 = __builtin_amdgcn_cvt_pk_f32_fp8((int)vB, false);
        const f32x2 vB23 = __builtin_amdgcn_cvt_pk_f32_fp8((int)vB, true);

        const float exA = __expf(pA - 4.0f);
        accA[0] += exA * vA01[0];
        accA[1] += exA * vA01[1];
        accA[2] += exA * vA23[0];
        accA[3] += exA * vA23[1];
        sA += exA;

        const float exB = __expf(pB - 4.0f);
        accB[0] += exB * vB01[0];
        accB[1] += exB * vB01[1];
        accB[2] += exB * vB23[0];
        accB[3] += exB * vB23[1];
        sB += exB;

        kA = nkA; vA = nvA; kB = nkB; vB = nvB;
        i = ni;
    }
    if (i < end) {  // odd tail -> chain A
        const f32x2 kA01 = __builtin_amdgcn_cvt_pk_f32_fp8((int)kA, false);
        const f32x2 kA23 = __builtin_amdgcn_cvt_pk_f32_fp8((int)kA, true);
        float pA = q0 * kA01[0] + q1v * kA01[1] + q2 * kA23[0] + q3 * kA23[1];
        pA += __shfl_xor(pA, 4, 8);
        pA += __shfl_xor(pA, 2, 8);
        pA += __shfl_xor(pA, 1, 8);
        const f32x2 vA01 = __builtin_amdgcn_cvt_pk_f32_fp8((int)vA, false);
        const f32x2 vA23 = __builtin_amdgcn_cvt_pk_f32_fp8((int)vA, true);
        const float exA = __expf(pA - 4.0f);
        accA[0] += exA * vA01[0];
        accA[1] += exA * vA01[1];
        accA[2] += exA * vA23[0];
        accA[3] += exA * vA23[1];
        sA += exA;
    }

    const float inv = 1.f / (sA + sB + 1e-16f);
    const __half2 sk01 = *(const __half2*)(skiph + (size_t)d * 128 + ch4);
    const __half2 sk23 = *(const __half2*)(skiph + (size_t)d * 128 + ch4 + 2);
    const float2 s01 = __half22float2(sk01);
    const float2 s23 = __half22float2(sk23);
    const float o0 = elu1(s01.x + (accA[0] + accB[0]) * inv);
    const float o1 = elu1(s01.y + (accA[1] + accB[1]) * inv);
    const float o2 = elu1(s23.x + (accA[2] + accB[2]) * inv);
    const float o3 = elu1(s23.y + (accA[3] + accB[3]) * inv);
    __half2 h01 = __floats2half2_rn(o0, o1);
    __half2 h23 = __floats2half2_rn(o2, o3);
    uint2 u;
    u.x = *(unsigned*)&h01;
    u.y = *(unsigned*)&h23;
    *(uint2*)(hb + (size_t)d * 128 + ch4) = u;
}

// ---------- layer-2 projections via MFMA: h[N,128] @ W2t^T + bias2 ----------
__global__ __launch_bounds__(128) void node_l2_mfma(
    const __half* __restrict__ hb, const __half* __restrict__ W2t,
    const float* __restrict__ bias2,
    __half* __restrict__ q2h, __half* __restrict__ kv2h,
    float* __restrict__ out)
{
    const int t = threadIdx.x;
    const int wave = t >> 6;
    const int lane = t & 63;
    const int l = lane & 15;
    const int g = lane >> 4;  // 0..3
    const int wrow0 = blockIdx.x * 128 + wave * 64;
    if (wrow0 >= NN) return;
    const bool full = (wrow0 + 64 <= NN);

    f16x8 hf[4][4];
    #pragma unroll
    for (int rt = 0; rt < 4; ++rt) {
        int arow = wrow0 + rt * 16 + l;
        if (!full && arow >= NN) arow = NN - 1;
        #pragma unroll
        for (int kk = 0; kk < 4; ++kk)
            hf[rt][kk] = *(const f16x8*)((const _Float16*)hb + (size_t)arow * 128 + kk * 32 + g * 8);
    }

    #pragma unroll
    for (int ct = 0; ct < 4; ++ct) {
        const int col = ct * 16 + l;
        f16x8 wf[4];
        #pragma unroll
        for (int kk = 0; kk < 4; ++kk)
            wf[kk] = *(const f16x8*)((const _Float16*)W2t + (size_t)col * 128 + kk * 32 + g * 8);

        f32x4 acc[4];
        #pragma unroll
        for (int rt = 0; rt < 4; ++rt) acc[rt] = (f32x4){0.f, 0.f, 0.f, 0.f};
        #pragma unroll
        for (int kk = 0; kk < 4; ++kk)
            #pragma unroll
            for (int rt = 0; rt < 4; ++rt)
                acc[rt] = __builtin_amdgcn_mfma_f32_16x16x32_f16(wf[kk], hf[rt][kk], acc[rt], 0, 0, 0);

        const int c0 = g * 4;
        const float4 bias = *(const float4*)(bias2 + ct * 16 + c0);
        #pragma unroll
        for (int rt = 0; rt < 4; ++rt) {
            const int row = wrow0 + rt * 16 + l;
            if (full || row < NN) {
                float4 r;
                r.x = acc[rt][0] + bias.x;
                r.y = acc[rt][1] + bias.y;
                r.z = acc[rt][2] + bias.z;
                r.w = acc[rt][3] + bias.w;
                if (ct == 3) {
                    if (g < 2) {
                        *(float2*)(out + (size_t)row * 10 + c0) = make_float2(r.x, r.y);
                        *(float2*)(out + (size_t)row * 10 + c0 + 2) = make_float2(r.z, r.w);
                    } else if (g == 2) {
                        *(float2*)(out + (size_t)row * 10 + 8) = make_float2(r.x, r.y);
                    }
                } else {
                    __half* p = ct == 0 ? q2h + (size_t)row * 16 + c0
                              : kv2h + (size_t)row * 32 + (ct == 2 ? 16 : 0) + c0;
                    __half2 h01 = __floats2half2_rn(r.x, r.y);
                    __half2 h23 = __floats2half2_rn(r.z, r.w);
                    uint2 u;
                    u.x = *(unsigned*)&h01;
                    u.y = *(unsigned*)&h23;
                    *(uint2*)p = u;
                }
            }
        }
    }
}

// ---------- layer-2 fused attention: 4 lanes/dst x 4 fp16 channels/lane ----------
// zero-padded channels keep the 4-lane dot exact; 2-shfl reduce; 64 dsts/block.
__global__ __launch_bounds__(256) void node_attn2(
    const __half* __restrict__ q2h, const __half* __restrict__ kv2h,
    const int* __restrict__ rowptr, const int* __restrict__ esrc,
    float* __restrict__ out)  // pre-loaded with skip (h @ Ws2 + bs2)
{
    const int t = threadIdx.x;
    const int d = blockIdx.x * 64 + (t >> 2);
    if (d >= NN) return;
    const int c = t & 3;        // lane within dst
    const int ch4 = c << 2;     // channel base (4 channels/lane)
    const int beg = rowptr[d];
    const int end = rowptr[d + 1];

    float q0, q1v, q2v, q3v;
    {
        const __half2 qa = *(const __half2*)(q2h + (size_t)d * 16 + ch4);
        const __half2 qb = *(const __half2*)(q2h + (size_t)d * 16 + ch4 + 2);
        const float2 fa = __half22float2(qa);
        const float2 fb = __half22float2(qb);
        q0 = fa.x * 0.31622776601683794f;
        q1v = fa.y * 0.31622776601683794f;
        q2v = fb.x * 0.31622776601683794f;
        q3v = fb.y * 0.31622776601683794f;
    }

    f32x4 accA = {0.f, 0.f, 0.f, 0.f}, accB = {0.f, 0.f, 0.f, 0.f};
    float sA = 0.f, sB = 0.f;

    int i = beg;
    int sa = (i < end) ? esrc[i] : 0;
    int sb = (i + 1 < end) ? esrc[i + 1] : 0;
    uint2 kA = *(const uint2*)(kv2h + (size_t)sa * 32 + ch4);
    uint2 vA = *(const uint2*)(kv2h + (size_t)sa * 32 + 16 + ch4);
    uint2 kB = *(const uint2*)(kv2h + (size_t)sb * 32 + ch4);
    uint2 vB = *(const uint2*)(kv2h + (size_t)sb * 32 + 16 + ch4);

    while (i + 1 < end) {
        const int ni = i + 2;
        const int nsa = (ni < end) ? esrc[ni] : 0;
        const int nsb = (ni + 1 < end) ? esrc[ni + 1] : 0;
        const uint2 nkA = *(const uint2*)(kv2h + (size_t)nsa * 32 + ch4);
        const uint2 nvA = *(const uint2*)(kv2h + (size_t)nsa * 32 + 16 + ch4);
        const uint2 nkB = *(const uint2*)(kv2h + (size_t)nsb * 32 + ch4);
        const uint2 nvB = *(const uint2*)(kv2h + (size_t)nsb * 32 + 16 + ch4);

        const float2 kA01 = __half22float2(*(const __half2*)&kA.x);
        const float2 kA23 = __half22float2(*(const __half2*)&kA.y);
        const float2 kB01 = __half22float2(*(const __half2*)&kB.x);
        const float2 kB23 = __half22float2(*(const __half2*)&kB.y);

        float pA = q0 * kA01.x + q1v * kA01.y + q2v * kA23.x + q3v * kA23.y;
        float pB = q0 * kB01.x + q1v * kB01.y + q2v * kB23.x + q3v * kB23.y;
        pA += __shfl_xor(pA, 2, 4); pB += __shfl_xor(pB, 2, 4);
        pA += __shfl_xor(pA, 1, 4); pB += __shfl_xor(pB, 1, 4);

        const float2 vA01 = __half22float2(*(const __half2*)&vA.x);
        const float2 vA23 = __half22float2(*(const __half2*)&vA.y);
        const float2 vB01 = __half22float2(*(const __half2*)&vB.x);
        const float2 vB23 = __half22float2(*(const __half2*)&vB.y);

        const float exA = __expf(pA - 2.0f);
        accA[0] += exA * vA01.x;
        accA[1] += exA * vA01.y;
        accA[2] += exA * vA23.x;
        accA[3] += exA * vA23.y;
        sA += exA;

        const float exB = __expf(pB - 2.0f);
        accB[0] += exB * vB01.x;
        accB[1] += exB * vB01.y;
        accB[2] += exB * vB23.x;
        accB[3] += exB * vB23.y;
        sB += exB;

        kA = nkA; vA = nvA; kB = nkB; vB = nvB;
        i = ni;
    }
    if (i < end) {  // odd tail -> chain A
        const float2 kA01 = __half22float2(*(const __half2*)&kA.x);
        const float2 kA23 = __half22float2(*(const __half2*)&kA.y);
        float pA = q0 * kA01.x + q1v * kA01.y + q2v * kA23.x + q3v * kA23.y;
        pA += __shfl_xor(pA, 2, 4);
        pA += __shfl_xor(pA, 1, 4);
        const float2 vA01 = __half22float2(*(const __half2*)&vA.x);
        const float2 vA23 = __half22float2(*(const __half2*)&vA.y);
        const float exA = __expf(pA - 2.0f);
        accA[0] += exA * vA01.x;
        accA[1] += exA * vA01.y;
        accA[2] += exA * vA23.x;
        accA[3] += exA * vA23.y;
        sA += exA;
    }

    const float inv = 1.f / (sA + sB + 1e-16f);
    if (c < 2) {  // channels ch4..ch4+3 all valid (0..7)
        float2 o0 = *(float2*)(out + (size_t)d * 10 + ch4);
        float2 o1 = *(float2*)(out + (size_t)d * 10 + ch4 + 2);
        o0.x += (accA[0] + accB[0]) * inv;
        o0.y += (accA[1] + accB[1]) * inv;
        o1.x += (accA[2] + accB[2]) * inv;
        o1.y += (accA[3] + accB[3]) * inv;
        *(float2*)(out + (size_t)d * 10 + ch4) = o0;
        *(float2*)(out + (size_t)d * 10 + ch4 + 2) = o1;
    } else if (c == 2) {  // channels 8,9 only
        float2 o0 = *(float2*)(out + (size_t)d * 10 + 8);
        o0.x += (accA[0] + accB[0]) * inv;
        o0.y += (accA[1] + accB[1]) * inv;
        *(float2*)(out + (size_t)d * 10 + 8) = o0;
    }
}

extern "C" void kernel_launch(void* const* d_in, const int* in_sizes, int n_in,
                              void* d_out, int out_size, void* d_ws, size_t ws_size,
                              hipStream_t stream) {
    const float* x   = (const float*)d_in[0];
    const int*   ei  = (const int*)d_in[1];
    const float* Wq1 = (const float*)d_in[2];  const float* bq1 = (const float*)d_in[3];
    const float* Wk1 = (const float*)d_in[4];  const float* bk1 = (const float*)d_in[5];
    const float* Wv1 = (const float*)d_in[6];  const float* bv1 = (const float*)d_in[7];
    const float* Ws1 = (const float*)d_in[8];  const float* bs1 = (const float*)d_in[9];
    const float* Wq2 = (const float*)d_in[10]; const float* bq2 = (const float*)d_in[11];
    const float* Wk2 = (const float*)d_in[12]; const float* bk2 = (const float*)d_in[13];
    const float* Wv2 = (const float*)d_in[14]; const float* bv2 = (const float*)d_in[15];
    const float* Ws2 = (const float*)d_in[16]; const float* bs2 = (const float*)d_in[17];
    float* out = (float*)d_out;

    const int* src = ei;
    const int* dst = ei + EE;

    // workspace carve
    __half* xh    = (__half*)d_ws;                      // N*128 f16 (x)
    __half* q1h   = xh + (size_t)NN * 128;              // N*128 f16
    __half* skiph = q1h + (size_t)NN * 128;             // N*128 f16 (x @ Ws + bs)
    __half* hb    = skiph + (size_t)NN * 128;           // N*128 f16 (h)
    unsigned char* k8 = (unsigned char*)(hb + (size_t)NN * 128);  // N*128 fp8
    unsigned char* v8 = k8 + (size_t)NN * 128;          // N*128 fp8
    __half* Wt    = (__half*)(v8 + (size_t)NN * 128);   // 4*128*128 f16
    __half* W2t   = Wt + 4 * 128 * 128;                 // 64*128 f16
    __half* q2h   = W2t + 64 * 128;                     // N*16 f16 (padded)
    __half* kv2h  = q2h + (size_t)NN * 16;              // N*32 f16 (k|v packed)
    float* bias2  = (float*)(kv2h + (size_t)NN * 32);   // 64 f32
    int* deg      = (int*)(bias2 + 64);                 // N
    int* rowptr   = deg + NN;                           // N+1
    int* bcur     = rowptr + NN + 1;                    // NBK bucket cursors
    int* bsum     = bcur + NBK;                         // NB
    int* esrc     = bsum + NB;                          // E (src sorted by dst)
    unsigned* bpair = (unsigned*)(esrc + EE);           // E packed (dst<<16)|src

    // prep: streaming x->f16 with hidden histogram; weight repacks
    hipMemsetAsync(deg, 0, (size_t)NN * sizeof(int), stream);
    convert_x_deg<<<(NN * 32 + 255) / 256, 256, 0, stream>>>(x, xh, dst, deg);
    build_weights<<<64, 256, 0, stream>>>(Wq1, Wk1, Wv1, Ws1,
                                          Wq2, bq2, Wk2, bk2, Wv2, bv2, Ws2, bs2,
                                          Wt, W2t, bias2);

    // CSR build: scan -> rowptr+bucket cursors -> two-pass bucketed scatter
    block_sums<<<NB, 256, 0, stream>>>(deg, bsum);
    scan_bsums<<<1, 256, 0, stream>>>(bsum);
    write_rowptr<<<NB, 256, 0, stream>>>(deg, bsum, rowptr, bcur);
    bucket_stage<<<(EE + CH - 1) / CH, 256, 0, stream>>>(src, dst, bcur, bpair);
    bucket_scatter<<<NBK, 256, 0, stream>>>(bpair, rowptr, esrc);

    // layer 1 projections via MFMA (q/skip f16, k/v fp8, LDS-staged stores)
    gemm_l1_mfma<<<dim3((NN + 127) / 128, 2), 256, 0, stream>>>(
        xh, Wt, bq1, bk1, bv1, bs1, q1h, k8, v8, skiph);

    // fused layer-1 attention + skip + ELU -> h fp16 (32 lanes/dst, u32 fp8 loads)
    node_attn1<<<(NN + 7) / 8, 256, 0, stream>>>(q1h, k8, v8, rowptr, esrc, skiph, hb);

    // layer-2 projections via MFMA (s2 written directly to d_out)
    node_l2_mfma<<<(NN + 127) / 128, 128, 0, stream>>>(hb, W2t, bias2, q2h, kv2h, out);

    // fused layer-2 attention (4 lanes/dst, 4 ch/lane)
    node_attn2<<<(NN + 63) / 64, 256, 0, stream>>>(q2h, kv2h, rowptr, esrc, out);
}

// Round 22
// 187.219 us; speedup vs baseline: 1.0835x; 1.0835x over previous
//
#include <hip/hip_runtime.h>
#include <hip/hip_fp16.h>
#include <math.h>

#define NN 50000
#define EE 800000
#define NB 196   // ceil(NN/256)
#define NBK 128  // dst-range buckets
#define BKN 391  // nodes per bucket (128*391 = 50048 >= NN)
#define CH 4096  // edges per bucket_stage block
// IN_DIM = 128, HEADS*HIDDEN = 128, NUM_CLASSES = 10

typedef _Float16 f16x8 __attribute__((ext_vector_type(8)));
typedef float f32x4 __attribute__((ext_vector_type(4)));
typedef float f32x2 __attribute__((ext_vector_type(2)));

__device__ inline float elu1(float x) { return x > 0.f ? x : expm1f(x); }

// ---------- prep: x (f32) -> xh (f16), dst-degree histogram hidden under the stream ----------
__global__ __launch_bounds__(256) void convert_x_deg(
    const float* __restrict__ x, __half* __restrict__ xh,
    const int* __restrict__ dst, int* __restrict__ deg)
{
    const int i = blockIdx.x * 256 + threadIdx.x;  // float4 index
    if (i < NN * 32) {
        const float4 v = ((const float4*)x)[i];
        ((__half2*)xh)[i * 2] = __floats2half2_rn(v.x, v.y);
        ((__half2*)xh)[i * 2 + 1] = __floats2half2_rn(v.z, v.w);
    }
    if (i < EE) atomicAdd(&deg[dst[i]], 1);
}

// ---------- prep: W1 transpose (f16) + W2 pack (f16, zero-padded) in one kernel ----------
__global__ __launch_bounds__(256) void build_weights(
    const float* __restrict__ Wq, const float* __restrict__ Wk,
    const float* __restrict__ Wv, const float* __restrict__ Ws,
    const float* __restrict__ Wq2, const float* __restrict__ bq2,
    const float* __restrict__ Wk2, const float* __restrict__ bk2,
    const float* __restrict__ Wv2, const float* __restrict__ bv2,
    const float* __restrict__ Ws2, const float* __restrict__ bs2,
    __half* __restrict__ Wt, __half* __restrict__ W2t, float* __restrict__ bias2)
{
    const int idx = blockIdx.x * 256 + threadIdx.x;
    if (idx < 8192) {
        const int col = idx >> 7, k = idx & 127;
        const int m = col >> 4, j = col & 15;
        const float* W = m == 0 ? Wq2 : m == 1 ? Wk2 : m == 2 ? Wv2 : Ws2;
        W2t[idx] = (__half)(j < 10 ? W[k * 10 + j] : 0.f);
    }
    if (idx < 64) {
        const int m = idx >> 4, j = idx & 15;
        const float* b = m == 0 ? bq2 : m == 1 ? bk2 : m == 2 ? bv2 : bs2;
        bias2[idx] = j < 10 ? b[j] : 0.f;
    }
    __shared__ float tile[32][33];
    const int mat = blockIdx.x >> 4;
    const int tid = blockIdx.x & 15;
    const int k0 = (tid >> 2) * 32, c0 = (tid & 3) * 32;
    const float* W = mat == 0 ? Wq : mat == 1 ? Wk : mat == 2 ? Wv : Ws;
    const int r = threadIdx.x >> 5;   // 0..7
    const int c = threadIdx.x & 31;
    for (int rr = r; rr < 32; rr += 8) tile[rr][c] = W[(size_t)(k0 + rr) * 128 + c0 + c];
    __syncthreads();
    for (int rr = r; rr < 32; rr += 8)
        Wt[((size_t)mat * 128 + c0 + rr) * 128 + k0 + c] = (__half)tile[c][rr];
}

// ---------- CSR build: multi-block scan ----------
__global__ __launch_bounds__(256) void block_sums(
    const int* __restrict__ deg, int* __restrict__ bsum)
{
    __shared__ int ws[4];
    const int t = threadIdx.x;
    const int idx = blockIdx.x * 256 + t;
    int d = (idx < NN) ? deg[idx] : 0;
    #pragma unroll
    for (int off = 32; off; off >>= 1) d += __shfl_down(d, off, 64);
    if ((t & 63) == 0) ws[t >> 6] = d;
    __syncthreads();
    if (t == 0) bsum[blockIdx.x] = ws[0] + ws[1] + ws[2] + ws[3];
}

__global__ __launch_bounds__(256) void scan_bsums(int* __restrict__ bsum)
{
    __shared__ int s[256];
    const int t = threadIdx.x;
    int v = (t < NB) ? bsum[t] : 0;
    s[t] = v;
    __syncthreads();
    for (int off = 1; off < 256; off <<= 1) {
        int u = (t >= off) ? s[t - off] : 0;
        __syncthreads();
        s[t] += u;
        __syncthreads();
    }
    if (t < NB) bsum[t] = (t == 0) ? 0 : s[t - 1];
}

// rowptr + bucket cursors (bcur[b] = rowptr[b*BKN], bucket base in esrc/bpair)
__global__ __launch_bounds__(256) void write_rowptr(
    const int* __restrict__ deg, const int* __restrict__ bsum,
    int* __restrict__ rowptr, int* __restrict__ bcur)
{
    __shared__ int s[256];
    const int t = threadIdx.x;
    const int idx = blockIdx.x * 256 + t;
    const int d = (idx < NN) ? deg[idx] : 0;
    s[t] = d;
    __syncthreads();
    for (int off = 1; off < 256; off <<= 1) {
        int u = (t >= off) ? s[t - off] : 0;
        __syncthreads();
        s[t] += u;
        __syncthreads();
    }
    const int excl = ((t == 0) ? 0 : s[t - 1]) + bsum[blockIdx.x];
    if (idx < NN) {
        rowptr[idx] = excl;
        if (idx % BKN == 0) bcur[idx / BKN] = excl;
    }
    if (idx == NN - 1) rowptr[NN] = excl + d;  // == EE
}

// ---------- pass 1: bucket edges by dst range ----------
__global__ __launch_bounds__(256) void bucket_stage(
    const int* __restrict__ src, const int* __restrict__ dst,
    int* __restrict__ bcur, unsigned* __restrict__ bpair)
{
    __shared__ unsigned ep[CH];        // packed (dst<<16)|src
    __shared__ unsigned short eb[CH];  // bucket id
    __shared__ unsigned stg[CH];       // bucket-sorted
    __shared__ int cnt[NBK], off[NBK], pos[NBK], gbase[NBK];
    const int t = threadIdx.x;
    const int e0 = blockIdx.x * CH;
    const int n = min(CH, EE - e0);
    if (t < NBK) cnt[t] = 0;
    __syncthreads();
    for (int i = t; i < n; i += 256) {
        const int s = src[e0 + i], d = dst[e0 + i];
        ep[i] = (unsigned)s | ((unsigned)d << 16);
        const int b = d / BKN;
        eb[i] = (unsigned short)b;
        atomicAdd(&cnt[b], 1);
    }
    __syncthreads();
    if (t == 0) {
        int run = 0;
        for (int b = 0; b < NBK; ++b) { off[b] = run; pos[b] = run; run += cnt[b]; }
    }
    __syncthreads();
    if (t < NBK && cnt[t] > 0) gbase[t] = atomicAdd(&bcur[t], cnt[t]);
    __syncthreads();
    for (int i = t; i < n; i += 256) {
        const int b = eb[i];
        const int p = atomicAdd(&pos[b], 1);
        stg[p] = ep[i];
    }
    __syncthreads();
    for (int i = t; i < n; i += 256) {
        int lo = 0, hi = NBK - 1;
        while (lo < hi) { const int mid = (lo + hi + 1) >> 1; if (off[mid] <= i) lo = mid; else hi = mid - 1; }
        bpair[gbase[lo] + (i - off[lo])] = stg[i];
    }
}

// ---------- pass 2: one block per bucket; LDS cursors; esrc range exclusive ----------
__global__ __launch_bounds__(256) void bucket_scatter(
    const unsigned* __restrict__ bpair, const int* __restrict__ rowptr,
    int* __restrict__ esrc)
{
    __shared__ int lcur[BKN];
    const int b = blockIdx.x;
    const int n0 = b * BKN;
    const int n1 = min(NN, n0 + BKN);
    const int nn = n1 - n0;
    const int t = threadIdx.x;
    for (int i = t; i < nn; i += 256) lcur[i] = rowptr[n0 + i];
    __syncthreads();
    const int ebeg = rowptr[n0];
    const int eend = rowptr[n1];
    for (int i = ebeg + t; i < eend; i += 256) {
        const unsigned p = bpair[i];
        const int s = (int)(p & 0xFFFFu);
        const int d = (int)(p >> 16);
        const int pos = atomicAdd(&lcur[d - n0], 1);
        esrc[pos] = s;
    }
}

// ---------- layer-1 projections via MFMA: 2 mats per block, 64-row waves ----------
// q/skip f16; k/v fp8 e4m3. LDS-staged full-line stores. (R20 config: 128 thr —
// R21's 256-thr/32-row split regressed: per-wave efficiency beats occupancy here.)
__global__ __launch_bounds__(128) void gemm_l1_mfma(
    const __half* __restrict__ xh, const __half* __restrict__ Wt,
    const float* __restrict__ bq, const float* __restrict__ bk,
    const float* __restrict__ bv, const float* __restrict__ bs,
    __half* __restrict__ oqh, unsigned char* __restrict__ ok8,
    unsigned char* __restrict__ ov8, __half* __restrict__ osh)
{
    __shared__ __align__(16) unsigned char ldsraw[128 * 272];  // 34 KB
    const int pair = blockIdx.y;  // 0: mats {0(q f16),1(k fp8)}; 1: mats {2(v fp8),3(s f16)}
    const int t = threadIdx.x;
    const int wave = t >> 6;
    const int lane = t & 63;
    const int l = lane & 15;
    const int g = lane >> 4;  // 0..3
    const int brow0 = blockIdx.x * 128;
    const int wrow0 = brow0 + wave * 64;

    f16x8 xf[4][4];
    #pragma unroll
    for (int rt = 0; rt < 4; ++rt) {
        int arow = wrow0 + rt * 16 + l;
        if (arow >= NN) arow = NN - 1;  // clamp: garbage rows never stored
        #pragma unroll
        for (int kk = 0; kk < 4; ++kk)
            xf[rt][kk] = *(const f16x8*)((const _Float16*)xh + (size_t)arow * 128 + kk * 32 + g * 8);
    }

    for (int mi = 0; mi < 2; ++mi) {
        const int mat = pair * 2 + mi;
        const bool isfp8 = (mat == 1 || mat == 2);
        const float* b = mat == 0 ? bq : mat == 1 ? bk : mat == 2 ? bv : bs;
        const _Float16* wt = (const _Float16*)Wt + (size_t)mat * 128 * 128;

        f16x8 wf[4], wfn[4];
        #pragma unroll
        for (int kk = 0; kk < 4; ++kk)
            wf[kk] = *(const f16x8*)(wt + (size_t)l * 128 + kk * 32 + g * 8);

        for (int ct = 0; ct < 8; ++ct) {
            if (ct < 7) {
                const int ncol = (ct + 1) * 16 + l;
                #pragma unroll
                for (int kk = 0; kk < 4; ++kk)
                    wfn[kk] = *(const f16x8*)(wt + (size_t)ncol * 128 + kk * 32 + g * 8);
            }
            f32x4 acc[4];
            #pragma unroll
            for (int rt = 0; rt < 4; ++rt) acc[rt] = (f32x4){0.f, 0.f, 0.f, 0.f};
            #pragma unroll
            for (int kk = 0; kk < 4; ++kk)
                #pragma unroll
                for (int rt = 0; rt < 4; ++rt)
                    acc[rt] = __builtin_amdgcn_mfma_f32_16x16x32_f16(wf[kk], xf[rt][kk], acc[rt], 0, 0, 0);

            const int col0 = ct * 16 + g * 4;
            const float4 bias = *(const float4*)(b + col0);
            #pragma unroll
            for (int rt = 0; rt < 4; ++rt) {
                const int lrow = wave * 64 + rt * 16 + l;
                const float r0 = acc[rt][0] + bias.x;
                const float r1 = acc[rt][1] + bias.y;
                const float r2 = acc[rt][2] + bias.z;
                const float r3 = acc[rt][3] + bias.w;
                if (isfp8) {
                    int p = __builtin_amdgcn_cvt_pk_fp8_f32(r0, r1, 0, false);
                    p = __builtin_amdgcn_cvt_pk_fp8_f32(r2, r3, p, true);
                    *(int*)&ldsraw[lrow * 144 + col0] = p;       // 144B row stride
                } else {
                    __half2 h01 = __floats2half2_rn(r0, r1);
                    __half2 h23 = __floats2half2_rn(r2, r3);
                    uint2 u;
                    u.x = *(unsigned*)&h01;
                    u.y = *(unsigned*)&h23;
                    *(uint2*)&ldsraw[lrow * 272 + col0 * 2] = u; // 272B row stride
                }
            }
            #pragma unroll
            for (int kk = 0; kk < 4; ++kk) wf[kk] = wfn[kk];
        }

        __syncthreads();
        if (isfp8) {
            unsigned char* o = (mat == 1) ? ok8 : ov8;
            #pragma unroll
            for (int i = 0; i < 8; ++i) {
                const int idx = i * 128 + t;
                const int row = idx >> 3;
                const int seg = idx & 7;
                const int grow = brow0 + row;
                if (grow < NN)
                    *(uint4*)(o + (size_t)grow * 128 + seg * 16) = *(const uint4*)&ldsraw[row * 144 + seg * 16];
            }
        } else {
            __half* o = (mat == 0) ? oqh : osh;
            #pragma unroll
            for (int i = 0; i < 16; ++i) {
                const int idx = i * 128 + t;
                const int row = idx >> 4;
                const int seg = idx & 15;
                const int grow = brow0 + row;
                if (grow < NN)
                    *(uint4*)(o + (size_t)grow * 128 + seg * 8) = *(const uint4*)&ldsraw[row * 272 + seg * 16];
            }
        }
        __syncthreads();
    }
}

// ---------- layer-1 fused attention + skip + ELU -> h (fp16) ----------
// 32 lanes/dst x 4 fp8 channels/lane; head = 8 lanes -> 3-shfl reduce.
__global__ __launch_bounds__(256) void node_attn1(
    const __half* __restrict__ q1, const unsigned char* __restrict__ k8,
    const unsigned char* __restrict__ v8,
    const int* __restrict__ rowptr, const int* __restrict__ esrc,
    const __half* __restrict__ skiph,  // x @ Ws + bs (f16)
    __half* __restrict__ hb)           // out: h = elu(skip + attn), fp16
{
    const int t = threadIdx.x;
    const int d = blockIdx.x * 8 + (t >> 5);
    if (d >= NN) return;
    const int ch4 = (t & 31) << 2;  // channel base (4 channels/lane)

    const int beg = rowptr[d];
    const int end = rowptr[d + 1];

    float q0, q1v, q2, q3;
    {
        const __half2 qa = *(const __half2*)(q1 + (size_t)d * 128 + ch4);
        const __half2 qb = *(const __half2*)(q1 + (size_t)d * 128 + ch4 + 2);
        const float2 fa = __half22float2(qa);
        const float2 fb = __half22float2(qb);
        q0 = fa.x * 0.17677669529663687f;
        q1v = fa.y * 0.17677669529663687f;
        q2 = fb.x * 0.17677669529663687f;
        q3 = fb.y * 0.17677669529663687f;
    }

    f32x4 accA = {0.f, 0.f, 0.f, 0.f}, accB = {0.f, 0.f, 0.f, 0.f};
    float sA = 0.f, sB = 0.f;

    int i = beg;
    int sa = (i < end) ? esrc[i] : 0;
    int sb = (i + 1 < end) ? esrc[i + 1] : 0;
    unsigned kA = *(const unsigned*)(k8 + (size_t)sa * 128 + ch4);
    unsigned vA = *(const unsigned*)(v8 + (size_t)sa * 128 + ch4);
    unsigned kB = *(const unsigned*)(k8 + (size_t)sb * 128 + ch4);
    unsigned vB = *(const unsigned*)(v8 + (size_t)sb * 128 + ch4);

    while (i + 1 < end) {
        const int ni = i + 2;
        const int nsa = (ni < end) ? esrc[ni] : 0;
        const int nsb = (ni + 1 < end) ? esrc[ni + 1] : 0;
        const unsigned nkA = *(const unsigned*)(k8 + (size_t)nsa * 128 + ch4);
        const unsigned nvA = *(const unsigned*)(v8 + (size_t)nsa * 128 + ch4);
        const unsigned nkB = *(const unsigned*)(k8 + (size_t)nsb * 128 + ch4);
        const unsigned nvB = *(const unsigned*)(v8 + (size_t)nsb * 128 + ch4);

        const f32x2 kA01 = __builtin_amdgcn_cvt_pk_f32_fp8((int)kA, false);
        const f32x2 kA23 = __builtin_amdgcn_cvt_pk_f32_fp8((int)kA, true);
        const f32x2 kB01 = __builtin_amdgcn_cvt_pk_f32_fp8((int)kB, false);
        const f32x2 kB23 = __builtin_amdgcn_cvt_pk_f32_fp8((int)kB, true);

        float pA = q0 * kA01[0] + q1v * kA01[1] + q2 * kA23[0] + q3 * kA23[1];
        float pB = q0 * kB01[0] + q1v * kB01[1] + q2 * kB23[0] + q3 * kB23[1];
        pA += __shfl_xor(pA, 4, 8); pB += __shfl_xor(pB, 4, 8);
        pA += __shfl_xor(pA, 2, 8); pB += __shfl_xor(pB, 2, 8);
        pA += __shfl_xor(pA, 1, 8); pB += __shfl_xor(pB, 1, 8);

        const f32x2 vA01 = __builtin_amdgcn_cvt_pk_f32_fp8((int)vA, false);
        const f32x2 vA23 = __builtin_amdgcn_cvt_pk_f32_fp8((int)vA, true);
        const f32x2 vB01 = __builtin_amdgcn_cvt_pk_f32_fp8((int)vB, false);
        const f32x2 vB23 = __builtin_amdgcn_cvt_pk_f32_fp8((int)vB, true);

        const float exA = __expf(pA - 4.0f);
        accA[0] += exA * vA01[0];
        accA[1] += exA * vA01[1];
        accA[2] += exA * vA23[0];
        accA[3] += exA * vA23[1];
        sA += exA;

        const float exB = __expf(pB - 4.0f);
        accB[0] += exB * vB01[0];
        accB[1] += exB * vB01[1];
        accB[2] += exB * vB23[0];
        accB[3] += exB * vB23[1];
        sB += exB;

        kA = nkA; vA = nvA; kB = nkB; vB = nvB;
        i = ni;
    }
    if (i < end) {  // odd tail -> chain A
        const f32x2 kA01 = __builtin_amdgcn_cvt_pk_f32_fp8((int)kA, false);
        const f32x2 kA23 = __builtin_amdgcn_cvt_pk_f32_fp8((int)kA, true);
        float pA = q0 * kA01[0] + q1v * kA01[1] + q2 * kA23[0] + q3 * kA23[1];
        pA += __shfl_xor(pA, 4, 8);
        pA += __shfl_xor(pA, 2, 8);
        pA += __shfl_xor(pA, 1, 8);
        const f32x2 vA01 = __builtin_amdgcn_cvt_pk_f32_fp8((int)vA, false);
        const f32x2 vA23 = __builtin_amdgcn_cvt_pk_f32_fp8((int)vA, true);
        const float exA = __expf(pA - 4.0f);
        accA[0] += exA * vA01[0];
        accA[1] += exA * vA01[1];
        accA[2] += exA * vA23[0];
        accA[3] += exA * vA23[1];
        sA += exA;
    }

    const float inv = 1.f / (sA + sB + 1e-16f);
    const __half2 sk01 = *(const __half2*)(skiph + (size_t)d * 128 + ch4);
    const __half2 sk23 = *(const __half2*)(skiph + (size_t)d * 128 + ch4 + 2);
    const float2 s01 = __half22float2(sk01);
    const float2 s23 = __half22float2(sk23);
    const float o0 = elu1(s01.x + (accA[0] + accB[0]) * inv);
    const float o1 = elu1(s01.y + (accA[1] + accB[1]) * inv);
    const float o2 = elu1(s23.x + (accA[2] + accB[2]) * inv);
    const float o3 = elu1(s23.y + (accA[3] + accB[3]) * inv);
    __half2 h01 = __floats2half2_rn(o0, o1);
    __half2 h23 = __floats2half2_rn(o2, o3);
    uint2 u;
    u.x = *(unsigned*)&h01;
    u.y = *(unsigned*)&h23;
    *(uint2*)(hb + (size_t)d * 128 + ch4) = u;
}

// ---------- layer-2 projections via MFMA: h[N,128] @ W2t^T + bias2 ----------
__global__ __launch_bounds__(128) void node_l2_mfma(
    const __half* __restrict__ hb, const __half* __restrict__ W2t,
    const float* __restrict__ bias2,
    __half* __restrict__ q2h, __half* __restrict__ kv2h,
    float* __restrict__ out)
{
    const int t = threadIdx.x;
    const int wave = t >> 6;
    const int lane = t & 63;
    const int l = lane & 15;
    const int g = lane >> 4;  // 0..3
    const int wrow0 = blockIdx.x * 128 + wave * 64;
    if (wrow0 >= NN) return;
    const bool full = (wrow0 + 64 <= NN);

    f16x8 hf[4][4];
    #pragma unroll
    for (int rt = 0; rt < 4; ++rt) {
        int arow = wrow0 + rt * 16 + l;
        if (!full && arow >= NN) arow = NN - 1;
        #pragma unroll
        for (int kk = 0; kk < 4; ++kk)
            hf[rt][kk] = *(const f16x8*)((const _Float16*)hb + (size_t)arow * 128 + kk * 32 + g * 8);
    }

    #pragma unroll
    for (int ct = 0; ct < 4; ++ct) {
        const int col = ct * 16 + l;
        f16x8 wf[4];
        #pragma unroll
        for (int kk = 0; kk < 4; ++kk)
            wf[kk] = *(const f16x8*)((const _Float16*)W2t + (size_t)col * 128 + kk * 32 + g * 8);

        f32x4 acc[4];
        #pragma unroll
        for (int rt = 0; rt < 4; ++rt) acc[rt] = (f32x4){0.f, 0.f, 0.f, 0.f};
        #pragma unroll
        for (int kk = 0; kk < 4; ++kk)
            #pragma unroll
            for (int rt = 0; rt < 4; ++rt)
                acc[rt] = __builtin_amdgcn_mfma_f32_16x16x32_f16(wf[kk], hf[rt][kk], acc[rt], 0, 0, 0);

        const int c0 = g * 4;
        const float4 bias = *(const float4*)(bias2 + ct * 16 + c0);
        #pragma unroll
        for (int rt = 0; rt < 4; ++rt) {
            const int row = wrow0 + rt * 16 + l;
            if (full || row < NN) {
                float4 r;
                r.x = acc[rt][0] + bias.x;
                r.y = acc[rt][1] + bias.y;
                r.z = acc[rt][2] + bias.z;
                r.w = acc[rt][3] + bias.w;
                if (ct == 3) {
                    if (g < 2) {
                        *(float2*)(out + (size_t)row * 10 + c0) = make_float2(r.x, r.y);
                        *(float2*)(out + (size_t)row * 10 + c0 + 2) = make_float2(r.z, r.w);
                    } else if (g == 2) {
                        *(float2*)(out + (size_t)row * 10 + 8) = make_float2(r.x, r.y);
                    }
                } else {
                    __half* p = ct == 0 ? q2h + (size_t)row * 16 + c0
                              : kv2h + (size_t)row * 32 + (ct == 2 ? 16 : 0) + c0;
                    __half2 h01 = __floats2half2_rn(r.x, r.y);
                    __half2 h23 = __floats2half2_rn(r.z, r.w);
                    uint2 u;
                    u.x = *(unsigned*)&h01;
                    u.y = *(unsigned*)&h23;
                    *(uint2*)p = u;
                }
            }
        }
    }
}

// ---------- layer-2 fused attention: 8 lanes/dst, 4 chains, half2 loads ----------
__global__ __launch_bounds__(256) void node_attn2(
    const __half* __restrict__ q2h, const __half* __restrict__ kv2h,
    const int* __restrict__ rowptr, const int* __restrict__ esrc,
    float* __restrict__ out)  // pre-loaded with skip (h @ Ws2 + bs2)
{
    const int t = threadIdx.x;
    const int d = blockIdx.x * 32 + (t >> 3);
    if (d >= NN) return;
    const int c = t & 7;  // channel pair (2c, 2c+1)
    const int beg = rowptr[d];
    const int end = rowptr[d + 1];

    float2 qv = __half22float2(*(const __half2*)(q2h + (size_t)d * 16 + 2 * c));
    qv.x *= 0.31622776601683794f;  // fold 1/sqrt(10)
    qv.y *= 0.31622776601683794f;

    float2 acc[4];
    float ss[4];
    #pragma unroll
    for (int j = 0; j < 4; ++j) { acc[j] = make_float2(0.f, 0.f); ss[j] = 0.f; }

    int i = beg;
    __half2 kr[4], vr[4];
    #pragma unroll
    for (int j = 0; j < 4; ++j) {
        const int s = (i + j < end) ? esrc[i + j] : 0;
        kr[j] = *(const __half2*)(kv2h + (size_t)s * 32 + 2 * c);
        vr[j] = *(const __half2*)(kv2h + (size_t)s * 32 + 16 + 2 * c);
    }

    while (i + 3 < end) {
        const int ni = i + 4;
        __half2 nk[4], nv[4];
        #pragma unroll
        for (int j = 0; j < 4; ++j) {
            const int s = (ni + j < end) ? esrc[ni + j] : 0;
            nk[j] = *(const __half2*)(kv2h + (size_t)s * 32 + 2 * c);
            nv[j] = *(const __half2*)(kv2h + (size_t)s * 32 + 16 + 2 * c);
        }
        #pragma unroll
        for (int j = 0; j < 4; ++j) {
            const float2 kf = __half22float2(kr[j]);
            const float2 vf = __half22float2(vr[j]);
            float p = qv.x * kf.x + qv.y * kf.y;
            p += __shfl_xor(p, 4, 8);
            p += __shfl_xor(p, 2, 8);
            p += __shfl_xor(p, 1, 8);
            const float ex = __expf(p - 2.0f);
            acc[j].x += ex * vf.x;
            acc[j].y += ex * vf.y;
            ss[j] += ex;
        }
        #pragma unroll
        for (int j = 0; j < 4; ++j) { kr[j] = nk[j]; vr[j] = nv[j]; }
        i = ni;
    }
    for (; i < end; ++i) {
        const int s = esrc[i];
        const float2 kf = __half22float2(*(const __half2*)(kv2h + (size_t)s * 32 + 2 * c));
        const float2 vf = __half22float2(*(const __half2*)(kv2h + (size_t)s * 32 + 16 + 2 * c));
        float p = qv.x * kf.x + qv.y * kf.y;
        p += __shfl_xor(p, 4, 8);
        p += __shfl_xor(p, 2, 8);
        p += __shfl_xor(p, 1, 8);
        const float ex = __expf(p - 2.0f);
        acc[0].x += ex * vf.x;
        acc[0].y += ex * vf.y;
        ss[0] += ex;
    }

    if (c < 5) {
        const float ssum = ss[0] + ss[1] + ss[2] + ss[3];
        const float inv = 1.f / (ssum + 1e-16f);
        float2 o = *(float2*)(out + (size_t)d * 10 + 2 * c);
        o.x += (acc[0].x + acc[1].x + acc[2].x + acc[3].x) * inv;
        o.y += (acc[0].y + acc[1].y + acc[2].y + acc[3].y) * inv;
        *(float2*)(out + (size_t)d * 10 + 2 * c) = o;
    }
}

extern "C" void kernel_launch(void* const* d_in, const int* in_sizes, int n_in,
                              void* d_out, int out_size, void* d_ws, size_t ws_size,
                              hipStream_t stream) {
    const float* x   = (const float*)d_in[0];
    const int*   ei  = (const int*)d_in[1];
    const float* Wq1 = (const float*)d_in[2];  const float* bq1 = (const float*)d_in[3];
    const float* Wk1 = (const float*)d_in[4];  const float* bk1 = (const float*)d_in[5];
    const float* Wv1 = (const float*)d_in[6];  const float* bv1 = (const float*)d_in[7];
    const float* Ws1 = (const float*)d_in[8];  const float* bs1 = (const float*)d_in[9];
    const float* Wq2 = (const float*)d_in[10]; const float* bq2 = (const float*)d_in[11];
    const float* Wk2 = (const float*)d_in[12]; const float* bk2 = (const float*)d_in[13];
    const float* Wv2 = (const float*)d_in[14]; const float* bv2 = (const float*)d_in[15];
    const float* Ws2 = (const float*)d_in[16]; const float* bs2 = (const float*)d_in[17];
    float* out = (float*)d_out;

    const int* src = ei;
    const int* dst = ei + EE;

    // workspace carve
    __half* xh    = (__half*)d_ws;                      // N*128 f16 (x)
    __half* q1h   = xh + (size_t)NN * 128;              // N*128 f16
    __half* skiph = q1h + (size_t)NN * 128;             // N*128 f16 (x @ Ws + bs)
    __half* hb    = skiph + (size_t)NN * 128;           // N*128 f16 (h)
    unsigned char* k8 = (unsigned char*)(hb + (size_t)NN * 128);  // N*128 fp8
    unsigned char* v8 = k8 + (size_t)NN * 128;          // N*128 fp8
    __half* Wt    = (__half*)(v8 + (size_t)NN * 128);   // 4*128*128 f16
    __half* W2t   = Wt + 4 * 128 * 128;                 // 64*128 f16
    __half* q2h   = W2t + 64 * 128;                     // N*16 f16 (padded)
    __half* kv2h  = q2h + (size_t)NN * 16;              // N*32 f16 (k|v packed)
    float* bias2  = (float*)(kv2h + (size_t)NN * 32);   // 64 f32
    int* deg      = (int*)(bias2 + 64);                 // N
    int* rowptr   = deg + NN;                           // N+1
    int* bcur     = rowptr + NN + 1;                    // NBK bucket cursors
    int* bsum     = bcur + NBK;                         // NB
    int* esrc     = bsum + NB;                          // E (src sorted by dst)
    unsigned* bpair = (unsigned*)(esrc + EE);           // E packed (dst<<16)|src

    // prep: streaming x->f16 with hidden histogram; weight repacks
    hipMemsetAsync(deg, 0, (size_t)NN * sizeof(int), stream);
    convert_x_deg<<<(NN * 32 + 255) / 256, 256, 0, stream>>>(x, xh, dst, deg);
    build_weights<<<64, 256, 0, stream>>>(Wq1, Wk1, Wv1, Ws1,
                                          Wq2, bq2, Wk2, bk2, Wv2, bv2, Ws2, bs2,
                                          Wt, W2t, bias2);

    // CSR build: scan -> rowptr+bucket cursors -> two-pass bucketed scatter
    block_sums<<<NB, 256, 0, stream>>>(deg, bsum);
    scan_bsums<<<1, 256, 0, stream>>>(bsum);
    write_rowptr<<<NB, 256, 0, stream>>>(deg, bsum, rowptr, bcur);
    bucket_stage<<<(EE + CH - 1) / CH, 256, 0, stream>>>(src, dst, bcur, bpair);
    bucket_scatter<<<NBK, 256, 0, stream>>>(bpair, rowptr, esrc);

    // layer 1 projections via MFMA (q/skip f16, k/v fp8, LDS-staged stores)
    gemm_l1_mfma<<<dim3((NN + 127) / 128, 2), 128, 0, stream>>>(
        xh, Wt, bq1, bk1, bv1, bs1, q1h, k8, v8, skiph);

    // fused layer-1 attention + skip + ELU -> h fp16 (32 lanes/dst, u32 fp8 loads)
    node_attn1<<<(NN + 7) / 8, 256, 0, stream>>>(q1h, k8, v8, rowptr, esrc, skiph, hb);

    // layer-2 projections via MFMA (s2 written directly to d_out)
    node_l2_mfma<<<(NN + 127) / 128, 128, 0, stream>>>(hb, W2t, bias2, q2h, kv2h, out);

    // fused layer-2 attention (8 lanes/dst, 4 chains)
    node_attn2<<<(NN + 31) / 32, 256, 0, stream>>>(q2h, kv2h, rowptr, esrc, out);
}